// Round 1
// 77.572 us; speedup vs baseline: 1.0134x; 1.0134x over previous
//
#include <hip/hip_runtime.h>
#include <stdint.h>

// N=M=16384, D=64 fp32. dist[n,m]=a_sq[n]+b_sq[m]-2ab; out = sum_n min_m.
// R15: i8 exact-integer MFMA (main ~38->~27us). R16: 2-fg fold (->~25us).
// R17: step-2 role-swap prefetch of A (ds_read) and cinit (global).
// R18: (a) bsqi cinit moves to LDS (staged once, 2KB/block) -- the K-loop
// loses ALL global loads and vmcnt waits; prefetch chain is pure lgkmcnt,
// covered by one DOT (~290 MFMA cycles). (b) setprio(1) around the MFMA
// cluster (T5 regime: waves now have load/MFMA role diversity). (c) finish
// via per-point atomicMin in main -> finish reads 64KB instead of 2MB at
// 256-wave occupancy.
#define N_PTS 16384
#define TSPLITS 32
#define TO_TILES 16                  // 512 TO pts per ts = 16 tiles of 32
#define FGPB 16                      // fg-groups per block
#define NBLOCKS (TSPLITS * (256 / FGPB))   // 512 blocks = 2/CU

typedef __attribute__((ext_vector_type(4)))  int i32x4;
typedef __attribute__((ext_vector_type(16))) int i32x16;

__device__ __forceinline__ int imin(int a, int b) { return a < b ? a : b; }
__device__ __forceinline__ int itree16(i32x16 a) {
    int m0 = imin(imin(a[0],  a[1]),  a[2]);
    int m1 = imin(imin(a[3],  a[4]),  a[5]);
    int m2 = imin(imin(a[6],  a[7]),  a[8]);
    int m3 = imin(imin(a[9],  a[10]), a[11]);
    int m4 = imin(imin(a[12], a[13]), a[14]);
    int m5 = imin(imin(a[15], m0), m1);
    return imin(imin(imin(m2, m3), m4), m5);
}
__device__ __forceinline__ int q8(float x) {   // round-nearest, clamp
    int q = __float2int_rn(x);
    return q < -127 ? -127 : (q > 127 ? 127 : q);
}

// ---------- prep: fp32 -> i8 FRAGMENT-ORDER operands + norms --------------
// Fragment layout for mfma_i32_32x32x32_i8: chunk(st, kb, lane=h*32+m) of
// 16B; dim d -> kb=d>>5, h=(d>>4)&1, j=d&15.
__global__ __launch_bounds__(256) void prep_kernel(
        const float* __restrict__ from_pts, const float* __restrict__ to_pts,
        float* __restrict__ a_sq, int* __restrict__ bsqi,
        char* __restrict__ BfQ, char* __restrict__ AtoQ,
        int* __restrict__ pmin16, float* __restrict__ out) {
    int gid = blockIdx.x * 256 + threadIdx.x;   // 0 .. 524287
    if (gid < N_PTS) pmin16[gid] = 0x7FFFFFFF;  // ws is re-poisoned each iter
    int row = gid >> 3;                 // 0..32767 (FROM then TO)
    int sub = gid & 7;
    bool isFrom = row < N_PTS;
    int r = row & (N_PTS - 1);
    const float* src = isFrom ? from_pts : to_pts;
    float4 v0 = ((const float4*)src)[r * 16 + sub * 2];
    float4 v1 = ((const float4*)src)[r * 16 + sub * 2 + 1];
    float s = v0.x*v0.x + v0.y*v0.y + v0.z*v0.z + v0.w*v0.w
            + v1.x*v1.x + v1.y*v1.y + v1.z*v1.z + v1.w*v1.w;
    s += __shfl_xor(s, 1); s += __shfl_xor(s, 2); s += __shfl_xor(s, 4);
    float sc = isFrom ? -16.0f : 16.0f;  // FROM carries the minus sign
    int q0 = q8(v0.x*sc), q1 = q8(v0.y*sc), q2 = q8(v0.z*sc), q3 = q8(v0.w*sc);
    int q4 = q8(v1.x*sc), q5 = q8(v1.y*sc), q6 = q8(v1.z*sc), q7 = q8(v1.w*sc);
    int2 w;
    w.x = (q0 & 255) | ((q1 & 255) << 8) | ((q2 & 255) << 16) | (q3 << 24);
    w.y = (q4 & 255) | ((q5 & 255) << 8) | ((q6 & 255) << 16) | (q7 << 24);
    int st = r >> 5;                    // subtile / tile index (0..511)
    int m  = r & 31;
    int kb = sub >> 2, h = (sub >> 1) & 1, half8 = sub & 1;
    size_t off = (((size_t)st * 2 + kb) * 64 + h * 32 + m) * 16 + 8 * half8;
    if (isFrom) {
        *(int2*)(BfQ + off) = w;
        if (sub == 0) a_sq[r] = s;
    } else {
        *(int2*)(AtoQ + off) = w;
        // bsqi = round(128*bsq) in C/D-layout order
        if (sub == 0)
            bsqi[st * 32 + ((m >> 2) & 1) * 16 + (m & 3) + 4 * (m >> 3)] =
                __float2int_rn(128.0f * s);
    }
    if (gid == 0) out[0] = 0.0f;
}

// ---------- main: stage-once LDS (A + bsq), barrier-free i8 sweep ---------
__global__ __launch_bounds__(512, 4) void main_kernel(
        const char* __restrict__ BfQ, const char* __restrict__ AtoQ,
        const int* __restrict__ bsqi, int* __restrict__ pmin16) {
    // whole ts A-slice: 16 tiles x 2 kb-chunks x 1KB = 32 KB, + 2KB bsqi
    __shared__ __align__(16) char abuf[32768 + 2048];

    const int tid = threadIdx.x;
    const int lane = tid & 63;
    const int l31 = lane & 31;
    const int h   = lane >> 5;
    const int wv  = tid >> 6;           // wave 0..7
    const int ts  = blockIdx.x >> 4;    // 0..31
    const int bg  = blockIdx.x & 15;
    const int gtb = ts * TO_TILES;

    // stage A: 32 chunks of 1KB; wave wv DMAs chunks 4wv..4wv+3
    // (dest = wave-uniform base + lane*16 per the global_load_lds rule)
    #pragma unroll
    for (int j2 = 0; j2 < 4; j2++) {
        int j = wv * 4 + j2;                         // 0..31
        const char* g = AtoQ +
            (((size_t)(gtb + (j >> 1)) * 2 + (j & 1)) * 64 + lane) * 16;
        char* l = &abuf[j * 1024];
        __builtin_amdgcn_global_load_lds(
            (const __attribute__((address_space(1))) unsigned int*)g,
            (__attribute__((address_space(3))) unsigned int*)l, 16, 0, 0);
    }
    // stage bsqi slice for this ts: 512 ints = 2KB, linear
    if (wv == 0) {
        #pragma unroll
        for (int j = 0; j < 2; j++) {
            const int* g = bsqi + gtb * 32 + j * 256 + lane * 4;
            char* l = &abuf[32768 + j * 1024];
            __builtin_amdgcn_global_load_lds(
                (const __attribute__((address_space(1))) unsigned int*)g,
                (__attribute__((address_space(3))) unsigned int*)l, 16, 0, 0);
        }
    }
    __syncthreads();                    // the ONLY barrier

    // both fg-groups resident: fgA = bg*16+wv, fgB = fgA+8 (32 VGPRs)
    const int fgA = bg * FGPB + wv;
    const int fgB = fgA + 8;
    i32x4 B00[2], B01[2], B10[2], B11[2];
    #pragma unroll
    for (int kb = 0; kb < 2; kb++) {
        B00[kb] = *(const i32x4*)(BfQ + (((size_t)(2 * fgA)     * 2 + kb) * 64 + lane) * 16);
        B01[kb] = *(const i32x4*)(BfQ + (((size_t)(2 * fgA + 1) * 2 + kb) * 64 + lane) * 16);
        B10[kb] = *(const i32x4*)(BfQ + (((size_t)(2 * fgB)     * 2 + kb) * 64 + lane) * 16);
        B11[kb] = *(const i32x4*)(BfQ + (((size_t)(2 * fgB + 1) * 2 + kb) * 64 + lane) * 16);
    }
    int rmin00 = 0x7FFFFFFF, rmin01 = 0x7FFFFFFF;
    int rmin10 = 0x7FFFFFFF, rmin11 = 0x7FFFFFFF;

    // ---- step-2 role-swap pipeline: A + cinit, both LDS, 1 tile ahead
    #define LOADT(T, A, CU)                                                     \
        {                                                                       \
            int t_ = (T);                                                       \
            A[0] = *(const i32x4*)&abuf[((t_ * 2 + 0) * 64 + lane) * 16];       \
            A[1] = *(const i32x4*)&abuf[((t_ * 2 + 1) * 64 + lane) * 16];       \
            const char* cb_ = &abuf[32768 + t_ * 128 + h * 64];                 \
            union { i32x4 f[4]; i32x16 v; } cu_;                                \
            cu_.f[0] = *(const i32x4*)(cb_ + 0);                                \
            cu_.f[1] = *(const i32x4*)(cb_ + 16);                               \
            cu_.f[2] = *(const i32x4*)(cb_ + 32);                               \
            cu_.f[3] = *(const i32x4*)(cb_ + 48);                               \
            CU = cu_.v;                                                         \
        }
    #define DOT(A, CU)                                                          \
        {                                                                       \
            __builtin_amdgcn_s_setprio(1);                                      \
            i32x16 c0 = __builtin_amdgcn_mfma_i32_32x32x32_i8(A[0], B00[0], CU, 0, 0, 0); \
            i32x16 c1 = __builtin_amdgcn_mfma_i32_32x32x32_i8(A[0], B01[0], CU, 0, 0, 0); \
            c0 = __builtin_amdgcn_mfma_i32_32x32x32_i8(A[1], B00[1], c0, 0, 0, 0); \
            c1 = __builtin_amdgcn_mfma_i32_32x32x32_i8(A[1], B01[1], c1, 0, 0, 0); \
            rmin00 = imin(rmin00, itree16(c0));                                 \
            rmin01 = imin(rmin01, itree16(c1));                                 \
            i32x16 c2 = __builtin_amdgcn_mfma_i32_32x32x32_i8(A[0], B10[0], CU, 0, 0, 0); \
            i32x16 c3 = __builtin_amdgcn_mfma_i32_32x32x32_i8(A[0], B11[0], CU, 0, 0, 0); \
            c2 = __builtin_amdgcn_mfma_i32_32x32x32_i8(A[1], B10[1], c2, 0, 0, 0); \
            c3 = __builtin_amdgcn_mfma_i32_32x32x32_i8(A[1], B11[1], c3, 0, 0, 0); \
            __builtin_amdgcn_s_setprio(0);                                      \
            rmin10 = imin(rmin10, itree16(c2));                                 \
            rmin11 = imin(rmin11, itree16(c3));                                 \
        }

    i32x4 Aa[2], Ab[2];
    i32x16 cua, cub;
    LOADT(0, Aa, cua)
    #pragma unroll 1
    for (int t = 0; t < TO_TILES; t += 2) {
        LOADT(t + 1, Ab, cub)                  // in flight over tile t
        DOT(Aa, cua)
        LOADT((t + 2) & (TO_TILES - 1), Aa, cua)   // over tile t+1
        DOT(Ab, cub)
    }

    // cross-half min, then device-scope atomicMin: 32 writers/address total,
    // spread across the whole kernel tail -- finish only reads 64KB.
    rmin00 = imin(rmin00, __shfl_xor(rmin00, 32));
    rmin01 = imin(rmin01, __shfl_xor(rmin01, 32));
    rmin10 = imin(rmin10, __shfl_xor(rmin10, 32));
    rmin11 = imin(rmin11, __shfl_xor(rmin11, 32));
    if (lane < 32) {
        atomicMin(&pmin16[fgA * 64 + l31],      rmin00);
        atomicMin(&pmin16[fgA * 64 + 32 + l31], rmin01);
        atomicMin(&pmin16[fgB * 64 + l31],      rmin10);
        atomicMin(&pmin16[fgB * 64 + 32 + l31], rmin11);
    }
}

// ---------- finish: add a_sq, global sum (pmin16 already min-reduced) -----
__global__ __launch_bounds__(256) void finish_kernel(
        const float* __restrict__ a_sq, const int* __restrict__ pmin16,
        float* __restrict__ out) {
    int r = blockIdx.x * 256 + threadIdx.x;
    float v = a_sq[r] + (float)pmin16[r] * 0.0078125f;   // /128
    #pragma unroll
    for (int k = 1; k < 64; k <<= 1) v += __shfl_xor(v, k);
    __shared__ float red[4];
    if ((threadIdx.x & 63) == 0) red[threadIdx.x >> 6] = v;
    __syncthreads();
    if (threadIdx.x == 0)
        atomicAdd(out, red[0] + red[1] + red[2] + red[3]);
}

extern "C" void kernel_launch(void* const* d_in, const int* in_sizes, int n_in,
                              void* d_out, int out_size, void* d_ws, size_t ws_size,
                              hipStream_t stream) {
    const float* from_pts = (const float*)d_in[0];
    const float* to_pts   = (const float*)d_in[1];
    char* ws = (char*)d_ws;
    float* a_sq   = (float*)ws;                                //  64 KB
    int*   bsqi   = (int*)(ws + (64 << 10));                   //  64 KB
    int*   pmin16 = (int*)(ws + (128 << 10));                  //  64 KB
    char*  BfQ    = ws + (256 << 10);                          //   1 MB
    char*  AtoQ   = ws + (256 << 10) + (1 << 20);              //   1 MB

    prep_kernel<<<(2 * N_PTS * 8) / 256, 256, 0, stream>>>(
        from_pts, to_pts, a_sq, bsqi, BfQ, AtoQ, pmin16, (float*)d_out);
    main_kernel<<<NBLOCKS, 512, 0, stream>>>(BfQ, AtoQ, bsqi, pmin16);
    finish_kernel<<<N_PTS / 256, 256, 0, stream>>>(a_sq, pmin16, (float*)d_out);
}

// Round 3
// 73.430 us; speedup vs baseline: 1.0706x; 1.0564x over previous
//
#include <hip/hip_runtime.h>
#include <stdint.h>

// N=M=16384, D=64 fp32. dist[n,m]=a_sq[n]+b_sq[m]-2ab; out = sum_n min_m.
// R15: i8 exact-integer MFMA (main ~38->~27us). R16: 2-fg fold (->~25us).
// R17: step-2 role-swap prefetch of A (ds_read) and cinit (global).
// R18: bsqi cinit in LDS; setprio around MFMA; atomicMin finish (+1us).
// R19 FAILED: v_min3_i32 inline asm (suspected MFMA->inline-asm-VALU read
// hazard not covered by the hazard recognizer) + skew together. Reverted
// the asm -- clang pattern-matches min3 from the plain tree anyway.
// R20: R18-exact reduction + per-wave tile skew ONLY (wave wv starts its
// sweep at tile 2*wv, wraps mod 16; min is order-independent). Breaks the
// post-barrier convoy where all 4 waves/SIMD run their VALU tree phase
// simultaneously and the MFMA pipe drains.
#define N_PTS 16384
#define TSPLITS 32
#define TO_TILES 16                  // 512 TO pts per ts = 16 tiles of 32
#define FGPB 16                      // fg-groups per block
#define NBLOCKS (TSPLITS * (256 / FGPB))   // 512 blocks = 2/CU

typedef __attribute__((ext_vector_type(4)))  int i32x4;
typedef __attribute__((ext_vector_type(16))) int i32x16;

__device__ __forceinline__ int imin(int a, int b) { return a < b ? a : b; }
__device__ __forceinline__ int itree16(i32x16 a) {
    int m0 = imin(imin(a[0],  a[1]),  a[2]);
    int m1 = imin(imin(a[3],  a[4]),  a[5]);
    int m2 = imin(imin(a[6],  a[7]),  a[8]);
    int m3 = imin(imin(a[9],  a[10]), a[11]);
    int m4 = imin(imin(a[12], a[13]), a[14]);
    int m5 = imin(imin(a[15], m0), m1);
    return imin(imin(imin(m2, m3), m4), m5);
}
__device__ __forceinline__ int q8(float x) {   // round-nearest, clamp
    int q = __float2int_rn(x);
    return q < -127 ? -127 : (q > 127 ? 127 : q);
}

// ---------- prep: fp32 -> i8 FRAGMENT-ORDER operands + norms --------------
// Fragment layout for mfma_i32_32x32x32_i8: chunk(st, kb, lane=h*32+m) of
// 16B; dim d -> kb=d>>5, h=(d>>4)&1, j=d&15.
__global__ __launch_bounds__(256) void prep_kernel(
        const float* __restrict__ from_pts, const float* __restrict__ to_pts,
        float* __restrict__ a_sq, int* __restrict__ bsqi,
        char* __restrict__ BfQ, char* __restrict__ AtoQ,
        int* __restrict__ pmin16, float* __restrict__ out) {
    int gid = blockIdx.x * 256 + threadIdx.x;   // 0 .. 524287
    if (gid < N_PTS) pmin16[gid] = 0x7FFFFFFF;  // ws is re-poisoned each iter
    int row = gid >> 3;                 // 0..32767 (FROM then TO)
    int sub = gid & 7;
    bool isFrom = row < N_PTS;
    int r = row & (N_PTS - 1);
    const float* src = isFrom ? from_pts : to_pts;
    float4 v0 = ((const float4*)src)[r * 16 + sub * 2];
    float4 v1 = ((const float4*)src)[r * 16 + sub * 2 + 1];
    float s = v0.x*v0.x + v0.y*v0.y + v0.z*v0.z + v0.w*v0.w
            + v1.x*v1.x + v1.y*v1.y + v1.z*v1.z + v1.w*v1.w;
    s += __shfl_xor(s, 1); s += __shfl_xor(s, 2); s += __shfl_xor(s, 4);
    float sc = isFrom ? -16.0f : 16.0f;  // FROM carries the minus sign
    int q0 = q8(v0.x*sc), q1 = q8(v0.y*sc), q2 = q8(v0.z*sc), q3 = q8(v0.w*sc);
    int q4 = q8(v1.x*sc), q5 = q8(v1.y*sc), q6 = q8(v1.z*sc), q7 = q8(v1.w*sc);
    int2 w;
    w.x = (q0 & 255) | ((q1 & 255) << 8) | ((q2 & 255) << 16) | (q3 << 24);
    w.y = (q4 & 255) | ((q5 & 255) << 8) | ((q6 & 255) << 16) | (q7 << 24);
    int st = r >> 5;                    // subtile / tile index (0..511)
    int m  = r & 31;
    int kb = sub >> 2, h = (sub >> 1) & 1, half8 = sub & 1;
    size_t off = (((size_t)st * 2 + kb) * 64 + h * 32 + m) * 16 + 8 * half8;
    if (isFrom) {
        *(int2*)(BfQ + off) = w;
        if (sub == 0) a_sq[r] = s;
    } else {
        *(int2*)(AtoQ + off) = w;
        // bsqi = round(128*bsq) in C/D-layout order
        if (sub == 0)
            bsqi[st * 32 + ((m >> 2) & 1) * 16 + (m & 3) + 4 * (m >> 3)] =
                __float2int_rn(128.0f * s);
    }
    if (gid == 0) out[0] = 0.0f;
}

// ---------- main: stage-once LDS (A + bsq), skewed barrier-free i8 sweep --
__global__ __launch_bounds__(512, 4) void main_kernel(
        const char* __restrict__ BfQ, const char* __restrict__ AtoQ,
        const int* __restrict__ bsqi, int* __restrict__ pmin16) {
    // whole ts A-slice: 16 tiles x 2 kb-chunks x 1KB = 32 KB, + 2KB bsqi
    __shared__ __align__(16) char abuf[32768 + 2048];

    const int tid = threadIdx.x;
    const int lane = tid & 63;
    const int l31 = lane & 31;
    const int h   = lane >> 5;
    const int wv  = tid >> 6;           // wave 0..7
    const int ts  = blockIdx.x >> 4;    // 0..31
    const int bg  = blockIdx.x & 15;
    const int gtb = ts * TO_TILES;

    // stage A: 32 chunks of 1KB; wave wv DMAs chunks 4wv..4wv+3
    // (dest = wave-uniform base + lane*16 per the global_load_lds rule)
    #pragma unroll
    for (int j2 = 0; j2 < 4; j2++) {
        int j = wv * 4 + j2;                         // 0..31
        const char* g = AtoQ +
            (((size_t)(gtb + (j >> 1)) * 2 + (j & 1)) * 64 + lane) * 16;
        char* l = &abuf[j * 1024];
        __builtin_amdgcn_global_load_lds(
            (const __attribute__((address_space(1))) unsigned int*)g,
            (__attribute__((address_space(3))) unsigned int*)l, 16, 0, 0);
    }
    // stage bsqi slice for this ts: 512 ints = 2KB, linear
    if (wv == 0) {
        #pragma unroll
        for (int j = 0; j < 2; j++) {
            const int* g = bsqi + gtb * 32 + j * 256 + lane * 4;
            char* l = &abuf[32768 + j * 1024];
            __builtin_amdgcn_global_load_lds(
                (const __attribute__((address_space(1))) unsigned int*)g,
                (__attribute__((address_space(3))) unsigned int*)l, 16, 0, 0);
        }
    }
    __syncthreads();                    // the ONLY barrier

    // both fg-groups resident: fgA = bg*16+wv, fgB = fgA+8 (32 VGPRs)
    const int fgA = bg * FGPB + wv;
    const int fgB = fgA + 8;
    i32x4 B00[2], B01[2], B10[2], B11[2];
    #pragma unroll
    for (int kb = 0; kb < 2; kb++) {
        B00[kb] = *(const i32x4*)(BfQ + (((size_t)(2 * fgA)     * 2 + kb) * 64 + lane) * 16);
        B01[kb] = *(const i32x4*)(BfQ + (((size_t)(2 * fgA + 1) * 2 + kb) * 64 + lane) * 16);
        B10[kb] = *(const i32x4*)(BfQ + (((size_t)(2 * fgB)     * 2 + kb) * 64 + lane) * 16);
        B11[kb] = *(const i32x4*)(BfQ + (((size_t)(2 * fgB + 1) * 2 + kb) * 64 + lane) * 16);
    }
    int rmin00 = 0x7FFFFFFF, rmin01 = 0x7FFFFFFF;
    int rmin10 = 0x7FFFFFFF, rmin11 = 0x7FFFFFFF;

    // ---- step-2 role-swap pipeline, per-wave tile skew: wave wv starts
    // at tile 2*wv (mod 16); min over all tiles is order-independent.
    const int toff = wv * 2;
    #define LOADT(T, A, CU)                                                     \
        {                                                                       \
            int t_ = (T) & (TO_TILES - 1);                                      \
            A[0] = *(const i32x4*)&abuf[((t_ * 2 + 0) * 64 + lane) * 16];       \
            A[1] = *(const i32x4*)&abuf[((t_ * 2 + 1) * 64 + lane) * 16];       \
            const char* cb_ = &abuf[32768 + t_ * 128 + h * 64];                 \
            union { i32x4 f[4]; i32x16 v; } cu_;                                \
            cu_.f[0] = *(const i32x4*)(cb_ + 0);                                \
            cu_.f[1] = *(const i32x4*)(cb_ + 16);                               \
            cu_.f[2] = *(const i32x4*)(cb_ + 32);                               \
            cu_.f[3] = *(const i32x4*)(cb_ + 48);                               \
            CU = cu_.v;                                                         \
        }
    #define DOT(A, CU)                                                          \
        {                                                                       \
            __builtin_amdgcn_s_setprio(1);                                      \
            i32x16 c0 = __builtin_amdgcn_mfma_i32_32x32x32_i8(A[0], B00[0], CU, 0, 0, 0); \
            i32x16 c1 = __builtin_amdgcn_mfma_i32_32x32x32_i8(A[0], B01[0], CU, 0, 0, 0); \
            c0 = __builtin_amdgcn_mfma_i32_32x32x32_i8(A[1], B00[1], c0, 0, 0, 0); \
            c1 = __builtin_amdgcn_mfma_i32_32x32x32_i8(A[1], B01[1], c1, 0, 0, 0); \
            rmin00 = imin(rmin00, itree16(c0));                                 \
            rmin01 = imin(rmin01, itree16(c1));                                 \
            i32x16 c2 = __builtin_amdgcn_mfma_i32_32x32x32_i8(A[0], B10[0], CU, 0, 0, 0); \
            i32x16 c3 = __builtin_amdgcn_mfma_i32_32x32x32_i8(A[0], B11[0], CU, 0, 0, 0); \
            c2 = __builtin_amdgcn_mfma_i32_32x32x32_i8(A[1], B10[1], c2, 0, 0, 0); \
            c3 = __builtin_amdgcn_mfma_i32_32x32x32_i8(A[1], B11[1], c3, 0, 0, 0); \
            __builtin_amdgcn_s_setprio(0);                                      \
            rmin10 = imin(rmin10, itree16(c2));                                 \
            rmin11 = imin(rmin11, itree16(c3));                                 \
        }

    i32x4 Aa[2], Ab[2];
    i32x16 cua, cub;
    LOADT(toff, Aa, cua)
    #pragma unroll 1
    for (int t = 0; t < TO_TILES; t += 2) {
        LOADT(toff + t + 1, Ab, cub)           // in flight over tile t
        DOT(Aa, cua)
        LOADT(toff + t + 2, Aa, cua)           // over tile t+1
        DOT(Ab, cub)
    }

    // cross-half min, then device-scope atomicMin: 32 writers/address total,
    // spread across the whole kernel tail -- finish only reads 64KB.
    rmin00 = imin(rmin00, __shfl_xor(rmin00, 32));
    rmin01 = imin(rmin01, __shfl_xor(rmin01, 32));
    rmin10 = imin(rmin10, __shfl_xor(rmin10, 32));
    rmin11 = imin(rmin11, __shfl_xor(rmin11, 32));
    if (lane < 32) {
        atomicMin(&pmin16[fgA * 64 + l31],      rmin00);
        atomicMin(&pmin16[fgA * 64 + 32 + l31], rmin01);
        atomicMin(&pmin16[fgB * 64 + l31],      rmin10);
        atomicMin(&pmin16[fgB * 64 + 32 + l31], rmin11);
    }
}

// ---------- finish: add a_sq, global sum (pmin16 already min-reduced) -----
__global__ __launch_bounds__(256) void finish_kernel(
        const float* __restrict__ a_sq, const int* __restrict__ pmin16,
        float* __restrict__ out) {
    int r = blockIdx.x * 256 + threadIdx.x;
    float v = a_sq[r] + (float)pmin16[r] * 0.0078125f;   // /128
    #pragma unroll
    for (int k = 1; k < 64; k <<= 1) v += __shfl_xor(v, k);
    __shared__ float red[4];
    if ((threadIdx.x & 63) == 0) red[threadIdx.x >> 6] = v;
    __syncthreads();
    if (threadIdx.x == 0)
        atomicAdd(out, red[0] + red[1] + red[2] + red[3]);
}

extern "C" void kernel_launch(void* const* d_in, const int* in_sizes, int n_in,
                              void* d_out, int out_size, void* d_ws, size_t ws_size,
                              hipStream_t stream) {
    const float* from_pts = (const float*)d_in[0];
    const float* to_pts   = (const float*)d_in[1];
    char* ws = (char*)d_ws;
    float* a_sq   = (float*)ws;                                //  64 KB
    int*   bsqi   = (int*)(ws + (64 << 10));                   //  64 KB
    int*   pmin16 = (int*)(ws + (128 << 10));                  //  64 KB
    char*  BfQ    = ws + (256 << 10);                          //   1 MB
    char*  AtoQ   = ws + (256 << 10) + (1 << 20);              //   1 MB

    prep_kernel<<<(2 * N_PTS * 8) / 256, 256, 0, stream>>>(
        from_pts, to_pts, a_sq, bsqi, BfQ, AtoQ, pmin16, (float*)d_out);
    main_kernel<<<NBLOCKS, 512, 0, stream>>>(BfQ, AtoQ, bsqi, pmin16);
    finish_kernel<<<N_PTS / 256, 256, 0, stream>>>(a_sq, pmin16, (float*)d_out);
}